// Round 1
// baseline (722.304 us; speedup 1.0000x reference)
//
#include <hip/hip_runtime.h>
#include <float.h>

// Sparsemax attention, fp32 in/out. B=64, Lq=Lk=1024, D=64.
// d_out = out[B,Lq,D] ++ attn[B,Lq,Lk], fp32.
//
// R9 = full fusion: score (MFMA) + sparsemax + sparse PV in ONE kernel.
//   - S tile (32 rows x 1024 keys, bf16) lives in LDS (64 KB); the 134 MB
//     sbuf HBM round-trip of R8 (write in score, read in pv) is gone.
//   - K staged per 64-key hi/lo tile (16 KB) via global_load_lds from the
//     pre-swizzled kbuf (kprep re-tiled to 64-key tiles), or cvt-in-loop
//     fallback when ws is small. Total LDS 80 KB -> 2 blocks/CU, 8 waves/CU
//     so PV-phase latency hiding survives.
//   - pbuf LDS broadcast replaced by __shfl(p[i], k): k is wave-uniform
//     (from ballot) -> readlane broadcast, no LDS.
//   - Numerics identical to R8: bf16-rne scores, fp32 Michelot + PV.

#define BATCH    64
#define SEQQ     1024
#define SEQK     1024
#define DHEAD    64

typedef short short8 __attribute__((ext_vector_type(8)));
typedef float f32x4  __attribute__((ext_vector_type(4)));
typedef unsigned short us4v __attribute__((ext_vector_type(4)));

typedef const __attribute__((address_space(1))) unsigned int as1_cuint;
typedef __attribute__((address_space(3))) unsigned int as3_uint;
typedef __attribute__((address_space(3))) unsigned char as3_uchar;

__device__ __forceinline__ unsigned short bf16_rne(float f) {
    unsigned u = __float_as_uint(f);
    u += 0x7fffu + ((u >> 16) & 1u);
    return (unsigned short)(u >> 16);
}

__device__ __forceinline__ void cvt_hilo8(const float* fv, float scale,
                                          short8* hi, short8* lo) {
    #pragma unroll
    for (int j = 0; j < 8; ++j) {
        float f = fv[j] * scale;
        unsigned short hb = bf16_rne(f);
        float hf = __uint_as_float((unsigned)hb << 16);
        (*hi)[j] = (short)hb;
        (*lo)[j] = (short)bf16_rne(f - hf);
    }
}

// ---- mask dtype detector: 1-byte bools vs int32 0/1 (proven R1-R8) --------
__global__ void detect_mask_fmt(const unsigned char* __restrict__ m,
                                int* __restrict__ flag) {
    __shared__ int s_found;
    if (threadIdx.x == 0) s_found = 0;
    __syncthreads();
    int found = 0;
    for (int o = threadIdx.x; o < 65536; o += 256) {
        if ((o & 3) != 0 && m[o] != 0) found = 1;
    }
    if (found) atomicOr(&s_found, 1);
    __syncthreads();
    if (threadIdx.x == 0) *flag = s_found;   // 1 => bytes, 0 => int32
}

// ---- kernel 0: K -> hi/lo bf16, pre-swizzled, 64-key tiles ----------------
// kbuf tile (b,kt): 8192 ushorts = [hi: key(64) x d(64) swizzled][lo: same].
__global__ __launch_bounds__(256) void kprep(
        const float* __restrict__ k, unsigned short* __restrict__ kbuf) {
    int gid  = blockIdx.x * 256 + threadIdx.x;    // [0, 64*1024*8)
    int db   = gid & 7;
    int keyg = (gid >> 3) & 1023;
    int b    = gid >> 13;
    int kt   = keyg >> 6;        // 16 tiles of 64 keys
    int key  = keyg & 63;

    const float4* src =
        (const float4*)(k + ((size_t)b * SEQK + keyg) * DHEAD + db * 8);
    float4 f0 = src[0], f1 = src[1];
    float fv[8] = {f0.x, f0.y, f0.z, f0.w, f1.x, f1.y, f1.z, f1.w};
    short8 hi, lo;
    cvt_hilo8(fv, 1.0f, &hi, &lo);

    unsigned short* tile = kbuf + (size_t)(b * 16 + kt) * 8192;
    int off = key * 64 + ((db ^ (key & 7)) * 8);   // ushort units
    *(short8*)(tile + off)        = hi;
    *(short8*)(tile + 4096 + off) = lo;
}

// ---- fused kernel: scores -> LDS, sparsemax, sparse PV --------------------
// grid 2048: x = qt*64 + b (x%8 = b%8 -> per-batch XCD pinning).
// 4 waves: wave = rowg(2) x keyh(2) in phase 1; 8 rows/wave in phase 2+3.
template<bool DMA>
__global__ __launch_bounds__(256, 2) void fused_attn(
        const float* __restrict__ q, const float* __restrict__ kmat,
        const unsigned short* __restrict__ kbuf,
        const float* __restrict__ v, const void* __restrict__ mask,
        const int* __restrict__ fmt_flag,
        float* __restrict__ out, float* __restrict__ attn) {
    const int lane = threadIdx.x & 63;
    const int wave = threadIdx.x >> 6;
    const int quad = lane >> 4;
    const int l15  = lane & 15;
    const int qt = blockIdx.x >> 6;     // [0,32) tiles of 32 q-rows
    const int b  = blockIdx.x & 63;

    __shared__ unsigned short slds[32 * 1024];  // 64 KB bf16 scores
    __shared__ unsigned short klds[8192];       // 16 KB K tile hi/lo

    const int rowg = wave & 1;   // which 16-row half
    const int keyh = wave >> 1;  // which 32-key half of the 64-key tile

    // ---- phase 1: S = (Q/8) K^T -> slds ----
    const float* qrow =
        q + ((size_t)b * SEQQ + qt * 32 + rowg * 16 + l15) * DHEAD;
    short8 a_hi[2], a_lo[2];
    #pragma unroll
    for (int kc = 0; kc < 2; ++kc) {
        const float4* src = (const float4*)(qrow + kc * 32 + quad * 8);
        float4 f0 = src[0], f1 = src[1];
        float fv[8] = {f0.x, f0.y, f0.z, f0.w, f1.x, f1.y, f1.z, f1.w};
        cvt_hilo8(fv, 0.125f, &a_hi[kc], &a_lo[kc]);
    }

    for (int kt = 0; kt < 16; ++kt) {
        __syncthreads();   // guard klds reuse across kt iterations
        if (DMA) {
            // DMA 16 KB tile: 4 waves x 4 calls x (64 lanes x 16 B)
            const unsigned char* gtile =
                (const unsigned char*)(kbuf + (size_t)(b * 16 + kt) * 8192);
            #pragma unroll
            for (int j = 0; j < 4; ++j) {
                unsigned off = wave * 4096 + j * 1024;   // wave-uniform
                as1_cuint* gp = (as1_cuint*)(gtile + off + lane * 16);
                as3_uint*  lp = (as3_uint*)((as3_uchar*)klds + off);
                __builtin_amdgcn_global_load_lds(gp, lp, 16, 0, 0);
            }
        } else {
            const float* kbase =
                kmat + ((size_t)b * SEQK + kt * 64) * DHEAD;
            #pragma unroll
            for (int it = 0; it < 2; ++it) {
                int e   = threadIdx.x + 256 * it;   // [0,512)
                int key = e >> 3, db = e & 7;
                const float4* src =
                    (const float4*)(kbase + key * DHEAD + db * 8);
                float4 f0 = src[0], f1 = src[1];
                float fv[8] = {f0.x, f0.y, f0.z, f0.w,
                               f1.x, f1.y, f1.z, f1.w};
                short8 hi, lo;
                cvt_hilo8(fv, 1.0f, &hi, &lo);
                int off = key * 64 + ((db ^ (key & 7)) * 8);
                *(short8*)(klds + off)        = hi;
                *(short8*)(klds + 4096 + off) = lo;
            }
        }
        __syncthreads();

        #pragma unroll
        for (int gg = 0; gg < 2; ++gg) {
            int g   = keyh * 2 + gg;
            int key = g * 16 + l15;           // [0,64) within tile
            short8 b_hi[2], b_lo[2];
            #pragma unroll
            for (int kc = 0; kc < 2; ++kc) {
                int db  = kc * 4 + quad;
                int off = key * 64 + ((db ^ (key & 7)) * 8);
                b_hi[kc] = *(const short8*)(klds + off);
                b_lo[kc] = *(const short8*)(klds + 4096 + off);
            }
            f32x4 acc = {0.f, 0.f, 0.f, 0.f};
            #pragma unroll
            for (int kc = 0; kc < 2; ++kc) {
                acc = __builtin_amdgcn_mfma_f32_16x16x32_bf16(a_hi[kc], b_hi[kc], acc, 0, 0, 0);
                acc = __builtin_amdgcn_mfma_f32_16x16x32_bf16(a_lo[kc], b_hi[kc], acc, 0, 0, 0);
                acc = __builtin_amdgcn_mfma_f32_16x16x32_bf16(a_hi[kc], b_lo[kc], acc, 0, 0, 0);
            }
            // C layout: col = l15, row = quad*4 + r
            #pragma unroll
            for (int r = 0; r < 4; ++r)
                slds[(rowg * 16 + quad * 4 + r) * 1024 +
                     kt * 64 + g * 16 + l15] = bf16_rne(acc[r]);
        }
    }
    __syncthreads();   // all 32 rows complete in slds

    // ---- phase 2+3: sparsemax + sparse PV, one row at a time per wave ----
    const int mask_is_byte = fmt_flag ? *fmt_flag : 1;
    const float* vbase = v + (size_t)b * SEQK * DHEAD;

    for (int rr = 0; rr < 8; ++rr) {
        const int    lrow = wave * 8 + rr;
        const size_t grow = (size_t)b * SEQQ + qt * 32 + lrow;
        float* arow = attn + grow * SEQK;

        // issue global mask loads first (long latency), then LDS scores
        unsigned mby[4];
        int mi32[16];
        if (mask_is_byte) {
            const unsigned* m32 =
                (const unsigned*)((const unsigned char*)mask + grow * SEQK);
            #pragma unroll
            for (int t = 0; t < 4; ++t)
                mby[t] = __builtin_nontemporal_load(m32 + lane + 64 * t);
        } else {
            const int* mi = (const int*)mask + grow * SEQK;
            #pragma unroll
            for (int t = 0; t < 4; ++t) {
                #pragma unroll
                for (int c = 0; c < 4; ++c)
                    mi32[4*t+c] = __builtin_nontemporal_load(
                        mi + 4 * (lane + 64 * t) + c);
            }
        }

        // lane holds keys 4*lane + 256*t + c (ds_read_b64, 2-way bank-free)
        float s[16];
        {
            const us4v* s4 = (const us4v*)(slds + lrow * 1024);
            #pragma unroll
            for (int t = 0; t < 4; ++t) {
                us4v u = s4[lane + 64 * t];
                s[4*t+0] = __uint_as_float((unsigned)u[0] << 16);
                s[4*t+1] = __uint_as_float((unsigned)u[1] << 16);
                s[4*t+2] = __uint_as_float((unsigned)u[2] << 16);
                s[4*t+3] = __uint_as_float((unsigned)u[3] << 16);
            }
        }

        if (mask_is_byte) {
            #pragma unroll
            for (int t = 0; t < 4; ++t) {
                if (mby[t] & 0x000000ffu) s[4*t+0] = -FLT_MAX;
                if (mby[t] & 0x0000ff00u) s[4*t+1] = -FLT_MAX;
                if (mby[t] & 0x00ff0000u) s[4*t+2] = -FLT_MAX;
                if (mby[t] & 0xff000000u) s[4*t+3] = -FLT_MAX;
            }
        } else {
            #pragma unroll
            for (int i = 0; i < 16; ++i)
                if (mi32[i]) s[i] = -FLT_MAX;
        }

        float mx = -FLT_MAX;
        #pragma unroll
        for (int i = 0; i < 16; ++i) mx = fmaxf(mx, s[i]);
        #pragma unroll
        for (int off = 32; off >= 1; off >>= 1)
            mx = fmaxf(mx, __shfl_xor(mx, off, 64));

        if (mx <= -FLT_MAX) {   // fully masked row -> zeros
            f32x4 z = {0.f, 0.f, 0.f, 0.f};
            #pragma unroll
            for (int t = 0; t < 4; ++t)
                __builtin_nontemporal_store(z, (f32x4*)arow + lane + 64 * t);
            out[grow * DHEAD + lane] = 0.f;
            continue;
        }

        // Michelot: seed thr = mx-1 (tau* >= mx-1); shrinks to exact support.
        float thr = mx - 1.0f, tau = 0.f;
        int cnt_prev = -1;
        for (int it = 0; it < 32; ++it) {
            float lsum = 0.f; int lcnt = 0;
            #pragma unroll
            for (int i = 0; i < 16; ++i)
                if (s[i] > thr) { lsum += s[i]; lcnt++; }
            #pragma unroll
            for (int off = 32; off >= 1; off >>= 1) {
                lsum += __shfl_xor(lsum, off, 64);
                lcnt += __shfl_xor(lcnt, off, 64);
            }
            tau = (lsum - 1.0f) / (float)lcnt;
            if (lcnt == cnt_prev) break;
            cnt_prev = lcnt;
            thr = tau;
        }

        // p; attn NT-store
        float p[16];
        #pragma unroll
        for (int i = 0; i < 16; ++i) {
            float pv = s[i] - tau;
            p[i] = pv > 0.f ? pv : 0.f;
        }
        #pragma unroll
        for (int t = 0; t < 4; ++t) {
            f32x4 f = {p[4*t+0], p[4*t+1], p[4*t+2], p[4*t+3]};
            __builtin_nontemporal_store(f, (f32x4*)arow + lane + 64 * t);
        }

        // sparse PV: group-of-4 extraction; p broadcast via __shfl
        // (k0..k3 are wave-uniform -> readlane, replaces R8's pbuf LDS).
        float oacc = 0.f;
        #pragma unroll
        for (int t = 0; t < 4; ++t) {
            #pragma unroll
            for (int c = 0; c < 4; ++c) {
                int i = 4 * t + c;
                unsigned long long mb = __ballot(p[i] > 0.f);
                while (mb) {
                    int k0, k1 = -1, k2 = -1, k3 = -1;
                    k0 = __ffsll(mb) - 1; mb &= mb - 1;
                    if (mb) { k1 = __ffsll(mb) - 1; mb &= mb - 1; }
                    if (mb) { k2 = __ffsll(mb) - 1; mb &= mb - 1; }
                    if (mb) { k3 = __ffsll(mb) - 1; mb &= mb - 1; }
                    float pj0 = __shfl(p[i], k0);
                    float v0  = vbase[(size_t)(4 * k0 + 256 * t + c) * DHEAD + lane];
                    float pj1 = 0.f, pj2 = 0.f, pj3 = 0.f;
                    float v1 = 0.f, v2 = 0.f, v3 = 0.f;
                    if (k1 >= 0) {
                        pj1 = __shfl(p[i], k1);
                        v1  = vbase[(size_t)(4 * k1 + 256 * t + c) * DHEAD + lane];
                    }
                    if (k2 >= 0) {
                        pj2 = __shfl(p[i], k2);
                        v2  = vbase[(size_t)(4 * k2 + 256 * t + c) * DHEAD + lane];
                    }
                    if (k3 >= 0) {
                        pj3 = __shfl(p[i], k3);
                        v3  = vbase[(size_t)(4 * k3 + 256 * t + c) * DHEAD + lane];
                    }
                    oacc = fmaf(pj0, v0, oacc);
                    if (k1 >= 0) oacc = fmaf(pj1, v1, oacc);
                    if (k2 >= 0) oacc = fmaf(pj2, v2, oacc);
                    if (k3 >= 0) oacc = fmaf(pj3, v3, oacc);
                }
            }
        }
        out[grow * DHEAD + lane] = oacc;
    }
}

extern "C" void kernel_launch(void* const* d_in, const int* in_sizes, int n_in,
                              void* d_out, int out_size, void* d_ws, size_t ws_size,
                              hipStream_t stream) {
    const float* q = (const float*)d_in[0];
    const float* k = (const float*)d_in[1];
    const float* v = (const float*)d_in[2];
    const void*  m = d_in[3];

    float* out  = (float*)d_out;
    float* attn = out + (size_t)BATCH * SEQQ * DHEAD;

    int* flag = nullptr;
    if (ws_size >= sizeof(int)) {
        flag = (int*)d_ws;
        detect_mask_fmt<<<1, 256, 0, stream>>>((const unsigned char*)m, flag);
    }

    // ws layout: [0,16) flag | [16, 16+K) K hi/lo pre-swizzled (64-key tiles)
    const size_t K_BYTES = (size_t)BATCH * SEQK * DHEAD * 2 * 2;   // 16 MB

    if (ws_size >= 16 + K_BYTES) {
        unsigned short* kbuf = (unsigned short*)((char*)d_ws + 16);
        kprep<<<(BATCH * SEQK * 8) / 256, 256, 0, stream>>>(k, kbuf);
        fused_attn<true><<<(SEQQ / 32) * BATCH, 256, 0, stream>>>(
            q, k, kbuf, v, m, flag, out, attn);
    } else {
        fused_attn<false><<<(SEQQ / 32) * BATCH, 256, 0, stream>>>(
            q, k, nullptr, v, m, flag, out, attn);
    }
}

// Round 2
// 638.816 us; speedup vs baseline: 1.1307x; 1.1307x over previous
//
#include <hip/hip_runtime.h>
#include <float.h>

// Sparsemax attention, fp32 in/out. B=64, Lq=Lk=1024, D=64.
// d_out = out[B,Lq,D] ++ attn[B,Lq,Lk], fp32.
//
// R10 = R8 (proven 643 us two-kernel structure) with:
//   a) score: SWAPPED MFMA operands (mfma(K,Q) instead of mfma(Q,K)) so
//      C row = key, col = q. Each lane then owns 4 consecutive keys of one
//      q-row -> 8B packed stores. 256 scalar 2B stores/thread -> 64x 8B.
//      Same product terms (KhiQhi+KhiQlo+KloQhi), same bf16_rne output.
//   b) pv: pbuf LDS broadcast replaced by __shfl(p[i],k) (k wave-uniform
//      -> readlane; verified in R9). Zero LDS in pv.
//   c) detect_mask_fmt merged into kprep (one extra block) -> one fewer
//      launch on the fast path.
// R9's full fusion REVERTED: it cut pv-phase occupancy 32->6.4 waves/CU
// (latency-bound phase needs TLP) and quadrupled phase-1 barrier overhead.

#define BATCH    64
#define SEQQ     1024
#define SEQK     1024
#define DHEAD    64

typedef short short8 __attribute__((ext_vector_type(8)));
typedef float f32x4  __attribute__((ext_vector_type(4)));
typedef unsigned short us4v __attribute__((ext_vector_type(4)));

typedef const __attribute__((address_space(1))) unsigned int as1_cuint;
typedef __attribute__((address_space(3))) unsigned int as3_uint;
typedef __attribute__((address_space(3))) unsigned char as3_uchar;

__device__ __forceinline__ unsigned short bf16_rne(float f) {
    unsigned u = __float_as_uint(f);
    u += 0x7fffu + ((u >> 16) & 1u);
    return (unsigned short)(u >> 16);
}

__device__ __forceinline__ void cvt_hilo8(const float* fv, float scale,
                                          short8* hi, short8* lo) {
    #pragma unroll
    for (int j = 0; j < 8; ++j) {
        float f = fv[j] * scale;
        unsigned short hb = bf16_rne(f);
        float hf = __uint_as_float((unsigned)hb << 16);
        (*hi)[j] = (short)hb;
        (*lo)[j] = (short)bf16_rne(f - hf);
    }
}

// ---- standalone mask detector (fallback path only) ------------------------
__global__ void detect_mask_fmt(const unsigned char* __restrict__ m,
                                int* __restrict__ flag) {
    __shared__ int s_found;
    if (threadIdx.x == 0) s_found = 0;
    __syncthreads();
    int found = 0;
    for (int o = threadIdx.x; o < 65536; o += 256) {
        if ((o & 3) != 0 && m[o] != 0) found = 1;
    }
    if (found) atomicOr(&s_found, 1);
    __syncthreads();
    if (threadIdx.x == 0) *flag = s_found;   // 1 => bytes, 0 => int32
}

// ---- kernel 0: K -> hi/lo bf16 pre-swizzled (128-key tiles) + detect ------
// kbuf tile (b,kt): 16384 ushorts = [hi: key(128) x d(64) swz][lo: same].
// Last block (idx == 2048) runs the mask-format detector instead.
__global__ __launch_bounds__(256) void kprep_detect(
        const float* __restrict__ k, unsigned short* __restrict__ kbuf,
        const unsigned char* __restrict__ m, int* __restrict__ flag) {
    if (blockIdx.x == (BATCH * SEQK * 8) / 256) {
        __shared__ int s_found;
        if (threadIdx.x == 0) s_found = 0;
        __syncthreads();
        int found = 0;
        for (int o = threadIdx.x; o < 65536; o += 256) {
            if ((o & 3) != 0 && m[o] != 0) found = 1;
        }
        if (found) atomicOr(&s_found, 1);
        __syncthreads();
        if (threadIdx.x == 0) *flag = s_found;
        return;
    }

    int gid  = blockIdx.x * 256 + threadIdx.x;    // [0, 64*1024*8)
    int db   = gid & 7;
    int keyg = (gid >> 3) & 1023;
    int b    = gid >> 13;
    int kt   = keyg >> 7;
    int key  = keyg & 127;

    const float4* src =
        (const float4*)(k + ((size_t)b * SEQK + keyg) * DHEAD + db * 8);
    float4 f0 = src[0], f1 = src[1];
    float fv[8] = {f0.x, f0.y, f0.z, f0.w, f1.x, f1.y, f1.z, f1.w};
    short8 hi, lo;
    cvt_hilo8(fv, 1.0f, &hi, &lo);

    unsigned short* tile = kbuf + (size_t)(b * 8 + kt) * 16384;
    int off = key * 64 + ((db ^ (key & 7)) * 8);   // ushort units
    *(short8*)(tile + off)        = hi;
    *(short8*)(tile + 8192 + off) = lo;
}

// ---- kernel A (fast path): scores via MFMA, DMA-staged K tiles ------------
// grid 1024: x = qt*64 + b (x%8 = b%8 -> per-batch XCD pinning).
// Swapped operands: C row = key (quad*4+r), col = q (l15) -> 8B stores.
__global__ __launch_bounds__(256) void score_kernel_dma(
        const float* __restrict__ q, const unsigned short* __restrict__ kbuf,
        unsigned short* __restrict__ sbuf, int pitch) {
    const int lane = threadIdx.x & 63;
    const int wave = threadIdx.x >> 6;
    const int quad = lane >> 4;
    const int l15  = lane & 15;
    const int qt = blockIdx.x >> 6;
    const int b  = blockIdx.x & 63;

    __shared__ unsigned short klds[2 * 128 * 64];   // 32 KB

    // Q B-frags once, scaled by 1/8, hi/lo split
    const float* qrow =
        q + ((size_t)b * SEQQ + qt * 64 + wave * 16 + l15) * DHEAD;
    short8 a_hi[2], a_lo[2];
    #pragma unroll
    for (int kc = 0; kc < 2; ++kc) {
        const float4* src = (const float4*)(qrow + kc * 32 + quad * 8);
        float4 f0 = src[0], f1 = src[1];
        float fv[8] = {f0.x, f0.y, f0.z, f0.w, f1.x, f1.y, f1.z, f1.w};
        cvt_hilo8(fv, 0.125f, &a_hi[kc], &a_lo[kc]);
    }

    // this lane's q-row (col = l15)
    unsigned short* srowq =
        sbuf + ((size_t)b * SEQQ + qt * 64 + wave * 16 + l15) * (size_t)pitch;

    for (int kt = 0; kt < 8; ++kt) {
        __syncthreads();   // guard klds reuse across kt iterations
        // DMA 32 KB tile: 4 waves x 8 calls x (64 lanes x 16 B)
        const unsigned char* gtile =
            (const unsigned char*)(kbuf + (size_t)(b * 8 + kt) * 16384);
        {
            unsigned base = wave * 8192 + lane * 16;
            #pragma unroll
            for (int j = 0; j < 8; ++j) {
                unsigned off = base + j * 1024;
                as1_cuint* gp = (as1_cuint*)(gtile + off);
                as3_uint*  lp = (as3_uint*)((as3_uchar*)klds +
                                            (wave * 8192 + j * 1024));
                __builtin_amdgcn_global_load_lds(gp, lp, 16, 0, 0);
            }
        }
        __syncthreads();

        #pragma unroll
        for (int g = 0; g < 8; ++g) {
            int key = g * 16 + l15;
            short8 b_hi[2], b_lo[2];
            #pragma unroll
            for (int kc = 0; kc < 2; ++kc) {
                int db  = kc * 4 + quad;
                int off = key * 64 + ((db ^ (key & 7)) * 8);
                b_hi[kc] = *(const short8*)(klds + off);
                b_lo[kc] = *(const short8*)(klds + 8192 + off);
            }
            f32x4 acc = {0.f, 0.f, 0.f, 0.f};
            #pragma unroll
            for (int kc = 0; kc < 2; ++kc) {
                acc = __builtin_amdgcn_mfma_f32_16x16x32_bf16(b_hi[kc], a_hi[kc], acc, 0, 0, 0);
                acc = __builtin_amdgcn_mfma_f32_16x16x32_bf16(b_hi[kc], a_lo[kc], acc, 0, 0, 0);
                acc = __builtin_amdgcn_mfma_f32_16x16x32_bf16(b_lo[kc], a_hi[kc], acc, 0, 0, 0);
            }
            // C layout (swapped): row = quad*4+r -> key, col = l15 -> q
            us4v pk;
            #pragma unroll
            for (int r = 0; r < 4; ++r) pk[r] = bf16_rne(acc[r]);
            *(us4v*)(srowq + kt * 128 + g * 16 + quad * 4) = pk;
        }
    }
}

// ---- kernel A (fallback): cvt-in-loop version, same swapped layout --------
__global__ __launch_bounds__(256) void score_kernel_cvt(
        const float* __restrict__ q, const float* __restrict__ k,
        unsigned short* __restrict__ sbuf, int pitch) {
    const int lane = threadIdx.x & 63;
    const int wave = threadIdx.x >> 6;
    const int quad = lane >> 4;
    const int l15  = lane & 15;
    const int qt = blockIdx.x >> 6;
    const int b  = blockIdx.x & 63;

    __shared__ unsigned short klds[2 * 128 * 64];

    const float* qrow =
        q + ((size_t)b * SEQQ + qt * 64 + wave * 16 + l15) * DHEAD;
    short8 a_hi[2], a_lo[2];
    #pragma unroll
    for (int kc = 0; kc < 2; ++kc) {
        const float4* src = (const float4*)(qrow + kc * 32 + quad * 8);
        float4 f0 = src[0], f1 = src[1];
        float fv[8] = {f0.x, f0.y, f0.z, f0.w, f1.x, f1.y, f1.z, f1.w};
        cvt_hilo8(fv, 0.125f, &a_hi[kc], &a_lo[kc]);
    }

    const float* kb = k + (size_t)b * SEQK * DHEAD;
    unsigned short* srowq =
        sbuf + ((size_t)b * SEQQ + qt * 64 + wave * 16 + l15) * (size_t)pitch;

    for (int kt = 0; kt < 8; ++kt) {
        __syncthreads();
        const float* kbase = kb + (size_t)kt * 128 * DHEAD;
        #pragma unroll
        for (int it = 0; it < 4; ++it) {
            int e   = threadIdx.x + 256 * it;
            int key = e >> 3, db = e & 7;
            const float4* src = (const float4*)(kbase + key * DHEAD + db * 8);
            float4 f0 = src[0], f1 = src[1];
            float fv[8] = {f0.x, f0.y, f0.z, f0.w, f1.x, f1.y, f1.z, f1.w};
            short8 hi, lo;
            cvt_hilo8(fv, 1.0f, &hi, &lo);
            int off = key * 64 + ((db ^ (key & 7)) * 8);
            *(short8*)(klds + off)        = hi;
            *(short8*)(klds + 8192 + off) = lo;
        }
        __syncthreads();

        #pragma unroll
        for (int g = 0; g < 8; ++g) {
            int key = g * 16 + l15;
            short8 b_hi[2], b_lo[2];
            #pragma unroll
            for (int kc = 0; kc < 2; ++kc) {
                int db  = kc * 4 + quad;
                int off = key * 64 + ((db ^ (key & 7)) * 8);
                b_hi[kc] = *(const short8*)(klds + off);
                b_lo[kc] = *(const short8*)(klds + 8192 + off);
            }
            f32x4 acc = {0.f, 0.f, 0.f, 0.f};
            #pragma unroll
            for (int kc = 0; kc < 2; ++kc) {
                acc = __builtin_amdgcn_mfma_f32_16x16x32_bf16(b_hi[kc], a_hi[kc], acc, 0, 0, 0);
                acc = __builtin_amdgcn_mfma_f32_16x16x32_bf16(b_hi[kc], a_lo[kc], acc, 0, 0, 0);
                acc = __builtin_amdgcn_mfma_f32_16x16x32_bf16(b_lo[kc], a_hi[kc], acc, 0, 0, 0);
            }
            us4v pk;
            #pragma unroll
            for (int r = 0; r < 4; ++r) pk[r] = bf16_rne(acc[r]);
            *(us4v*)(srowq + kt * 128 + g * 16 + quad * 4) = pk;
        }
    }
}

// ---- kernel B: sparsemax + sparse PV, one wave per row, zero LDS ----------
__global__ __launch_bounds__(256) void sparsemax_pv(
        const float* __restrict__ v, const void* __restrict__ mask,
        const int* __restrict__ fmt_flag,
        float* __restrict__ out, float* __restrict__ attn,
        const unsigned short* __restrict__ sbuf, int pitch) {
    const int lane = threadIdx.x & 63;
    const int wave = threadIdx.x >> 6;
    const int row  = blockIdx.x * 4 + wave;
    const int b    = row >> 10;
    float* arow = attn + (size_t)row * SEQK;
    const int mask_is_byte = fmt_flag ? *fmt_flag : 1;

    // lane holds keys 4*lane + 256*t + c (coalesced 8B, nontemporal)
    const us4v* s4 = (const us4v*)(sbuf + (size_t)row * (size_t)pitch);
    float s[16];
    #pragma unroll
    for (int t = 0; t < 4; ++t) {
        us4v u = __builtin_nontemporal_load(s4 + lane + 64 * t);
        s[4*t+0] = __uint_as_float((unsigned)u[0] << 16);
        s[4*t+1] = __uint_as_float((unsigned)u[1] << 16);
        s[4*t+2] = __uint_as_float((unsigned)u[2] << 16);
        s[4*t+3] = __uint_as_float((unsigned)u[3] << 16);
    }
    if (mask_is_byte) {
        const unsigned* m32 =
            (const unsigned*)((const unsigned char*)mask + (size_t)row * SEQK);
        #pragma unroll
        for (int t = 0; t < 4; ++t) {
            unsigned m = __builtin_nontemporal_load(m32 + lane + 64 * t);
            if (m & 0x000000ffu) s[4*t+0] = -FLT_MAX;
            if (m & 0x0000ff00u) s[4*t+1] = -FLT_MAX;
            if (m & 0x00ff0000u) s[4*t+2] = -FLT_MAX;
            if (m & 0xff000000u) s[4*t+3] = -FLT_MAX;
        }
    } else {
        const int* mi = (const int*)mask + (size_t)row * SEQK;
        #pragma unroll
        for (int t = 0; t < 4; ++t) {
            int m0 = __builtin_nontemporal_load(mi + 4 * (lane + 64 * t) + 0);
            int m1 = __builtin_nontemporal_load(mi + 4 * (lane + 64 * t) + 1);
            int m2 = __builtin_nontemporal_load(mi + 4 * (lane + 64 * t) + 2);
            int m3 = __builtin_nontemporal_load(mi + 4 * (lane + 64 * t) + 3);
            if (m0) s[4*t+0] = -FLT_MAX;
            if (m1) s[4*t+1] = -FLT_MAX;
            if (m2) s[4*t+2] = -FLT_MAX;
            if (m3) s[4*t+3] = -FLT_MAX;
        }
    }

    float mx = -FLT_MAX;
    #pragma unroll
    for (int i = 0; i < 16; ++i) mx = fmaxf(mx, s[i]);
    #pragma unroll
    for (int off = 32; off >= 1; off >>= 1)
        mx = fmaxf(mx, __shfl_xor(mx, off, 64));

    if (mx <= -FLT_MAX) {   // fully masked row -> zeros
        f32x4 z = {0.f, 0.f, 0.f, 0.f};
        #pragma unroll
        for (int t = 0; t < 4; ++t)
            __builtin_nontemporal_store(z, (f32x4*)arow + lane + 64 * t);
        out[(size_t)row * DHEAD + lane] = 0.f;
        return;
    }

    // Michelot: seed thr = mx-1 (tau* >= mx-1); shrinks to exact support.
    float thr = mx - 1.0f, tau = 0.f;
    int cnt_prev = -1;
    for (int it = 0; it < 32; ++it) {
        float lsum = 0.f; int lcnt = 0;
        #pragma unroll
        for (int i = 0; i < 16; ++i)
            if (s[i] > thr) { lsum += s[i]; lcnt++; }
        #pragma unroll
        for (int off = 32; off >= 1; off >>= 1) {
            lsum += __shfl_xor(lsum, off, 64);
            lcnt += __shfl_xor(lcnt, off, 64);
        }
        tau = (lsum - 1.0f) / (float)lcnt;
        if (lcnt == cnt_prev) break;
        cnt_prev = lcnt;
        thr = tau;
    }

    // p; attn NT-store
    float p[16];
    #pragma unroll
    for (int i = 0; i < 16; ++i) {
        float pv = s[i] - tau;
        p[i] = pv > 0.f ? pv : 0.f;
    }
    #pragma unroll
    for (int t = 0; t < 4; ++t) {
        f32x4 f = {p[4*t+0], p[4*t+1], p[4*t+2], p[4*t+3]};
        __builtin_nontemporal_store(f, (f32x4*)arow + lane + 64 * t);
    }

    // sparse PV: group-of-4 extraction; p broadcast via __shfl
    // (k0..k3 wave-uniform -> readlane; replaces R8's pbuf LDS).
    const float* vbase = v + (size_t)b * SEQK * DHEAD;
    float oacc = 0.f;
    #pragma unroll
    for (int t = 0; t < 4; ++t) {
        #pragma unroll
        for (int c = 0; c < 4; ++c) {
            int i = 4 * t + c;
            unsigned long long mb = __ballot(p[i] > 0.f);
            while (mb) {
                int k0, k1 = -1, k2 = -1, k3 = -1;
                k0 = __ffsll(mb) - 1; mb &= mb - 1;
                if (mb) { k1 = __ffsll(mb) - 1; mb &= mb - 1; }
                if (mb) { k2 = __ffsll(mb) - 1; mb &= mb - 1; }
                if (mb) { k3 = __ffsll(mb) - 1; mb &= mb - 1; }
                float pj0 = __shfl(p[i], k0);
                float v0  = vbase[(size_t)(4 * k0 + 256 * t + c) * DHEAD + lane];
                float pj1 = 0.f, pj2 = 0.f, pj3 = 0.f;
                float v1 = 0.f, v2 = 0.f, v3 = 0.f;
                if (k1 >= 0) {
                    pj1 = __shfl(p[i], k1);
                    v1  = vbase[(size_t)(4 * k1 + 256 * t + c) * DHEAD + lane];
                }
                if (k2 >= 0) {
                    pj2 = __shfl(p[i], k2);
                    v2  = vbase[(size_t)(4 * k2 + 256 * t + c) * DHEAD + lane];
                }
                if (k3 >= 0) {
                    pj3 = __shfl(p[i], k3);
                    v3  = vbase[(size_t)(4 * k3 + 256 * t + c) * DHEAD + lane];
                }
                oacc = fmaf(pj0, v0, oacc);
                if (k1 >= 0) oacc = fmaf(pj1, v1, oacc);
                if (k2 >= 0) oacc = fmaf(pj2, v2, oacc);
                if (k3 >= 0) oacc = fmaf(pj3, v3, oacc);
            }
        }
    }
    out[(size_t)row * DHEAD + lane] = oacc;
}

extern "C" void kernel_launch(void* const* d_in, const int* in_sizes, int n_in,
                              void* d_out, int out_size, void* d_ws, size_t ws_size,
                              hipStream_t stream) {
    const float* q = (const float*)d_in[0];
    const float* k = (const float*)d_in[1];
    const float* v = (const float*)d_in[2];
    const void*  m = d_in[3];

    float* out  = (float*)d_out;
    float* attn = out + (size_t)BATCH * SEQQ * DHEAD;

    int* flag = nullptr;
    if (ws_size >= sizeof(int)) flag = (int*)d_ws;

    // ws layout: [0,16) flag | [16, 16+S) S bf16 | [16+S, 16+S+K) K hi/lo
    const size_t S_BYTES = (size_t)BATCH * SEQQ * SEQK * 2;          // 134 MB
    const size_t K_BYTES = (size_t)BATCH * SEQK * DHEAD * 2 * 2;     // 16 MB

    unsigned short* sbuf;
    int pitch;
    bool s_in_ws = ws_size >= 16 + S_BYTES;
    if (s_in_ws) {
        sbuf  = (unsigned short*)d_ws + 8;
        pitch = SEQK;
    } else {
        sbuf  = (unsigned short*)attn;   // in-place, strided (proven R5)
        pitch = 2 * SEQK;
    }

    bool k_in_ws = s_in_ws && ws_size >= 16 + S_BYTES + K_BYTES;
    if (k_in_ws) {
        unsigned short* kbuf =
            (unsigned short*)((char*)d_ws + 16 + S_BYTES);
        // kprep + mask-format detect fused: one extra block does detect
        kprep_detect<<<(BATCH * SEQK * 8) / 256 + 1, 256, 0, stream>>>(
            k, kbuf, (const unsigned char*)m, flag);
        score_kernel_dma<<<(SEQQ / 64) * BATCH, 256, 0, stream>>>(
            q, kbuf, sbuf, pitch);
    } else {
        if (flag)
            detect_mask_fmt<<<1, 256, 0, stream>>>((const unsigned char*)m, flag);
        score_kernel_cvt<<<(SEQQ / 64) * BATCH, 256, 0, stream>>>(
            q, k, sbuf, pitch);
    }

    sparsemax_pv<<<(BATCH * SEQQ) / 4, 256, 0, stream>>>(
        v, m, flag, out, attn, sbuf, pitch);
}